// Round 1
// 465.483 us; speedup vs baseline: 1.1850x; 1.1850x over previous
//
#include <hip/hip_runtime.h>
#include <math.h>

// ---------- types ----------
typedef float  f32x4 __attribute__((ext_vector_type(4)));
typedef _Float16 f16x8 __attribute__((ext_vector_type(8)));
typedef _Float16 f16x4 __attribute__((ext_vector_type(4)));

__device__ __forceinline__ float gelu_f(float x) {
    return 0.5f * x * (1.0f + erff(x * 0.70710678118654752440f));
}

__device__ __forceinline__ f16x4 cvt4(float4 v) {
    f16x4 h;
    h.x = (_Float16)v.x; h.y = (_Float16)v.y;
    h.z = (_Float16)v.z; h.w = (_Float16)v.w;
    return h;
}

// ---------- weight_net: w[l] for lags -64..64 ----------
__global__ void weightnet_kernel(const float* __restrict__ w1, const float* __restrict__ b1,
                                 const float* __restrict__ w2, const float* __restrict__ b2,
                                 float* __restrict__ wout) {
    int l = threadIdx.x;
    if (l < 129) {
        float lag = (float)(l - 64);
        float acc = b2[0];
        for (int k = 0; k < 64; ++k) {
            float h = lag * w1[k] + b1[k];
            acc += gelu_f(h) * w2[k];
        }
        wout[l] = acc;
    }
}

// ---------- fused: row mean + center + 129-tap conv (register FIR) ----------
// Y[j,t] = sum_{l=0..128} w[l] * xpad[t+l], xpad = [64 zeros | Xc row | 64 zeros]
// __launch_bounds__(256): without it hipcc assumes 1024-thread blocks and caps
// VGPRs at 64 -> vbuf/xv/acc spill to scratch -> 254 MB of HBM traffic, 111 us.
__global__ __launch_bounds__(256)
void center_conv_kernel(const float* __restrict__ X,
                        const float* __restrict__ w, float* __restrict__ Xc,
                        float* __restrict__ Y, float* __restrict__ z) {
    __shared__ float xs[4224];            // 64 pad + 4096 + 64 pad
    __shared__ float wsm[132];
    __shared__ float ps[4];
    const int j = blockIdx.x, tid = threadIdx.x;
    float4* xs4 = (float4*)xs;

    if (tid < 64) { xs[tid] = 0.f; xs[4160 + tid] = 0.f; }
    if (tid < 132) wsm[tid] = (tid < 129) ? w[tid] : 0.f;

    const float4* Xr4 = (const float4*)(X + (size_t)j * 4096);
    float4* zr4 = (float4*)(z + (size_t)j * 8192);
    float s = 0.f;
    float4 vbuf[4];
    #pragma unroll
    for (int k = 0; k < 4; ++k) {
        int c4 = tid + k * 256;
        float4 v = Xr4[c4];
        vbuf[k] = v;
        xs4[16 + c4] = v;
        zr4[c4] = v;
        s += v.x + v.y + v.z + v.w;
    }
    #pragma unroll
    for (int o = 32; o > 0; o >>= 1) s += __shfl_down(s, o, 64);
    if ((tid & 63) == 0) ps[tid >> 6] = s;
    __syncthreads();
    const float m = (ps[0] + ps[1] + ps[2] + ps[3]) * (1.0f / 4096.0f);

    float4* Xc4 = (float4*)(Xc + (size_t)j * 4096);
    #pragma unroll
    for (int k = 0; k < 4; ++k) {
        int c4 = tid + k * 256;
        float4 v = vbuf[k];
        v.x -= m; v.y -= m; v.z -= m; v.w -= m;
        xs4[16 + c4] = v;
        Xc4[c4] = v;
    }
    __syncthreads();

    // conv: thread handles outputs t0 = 4*tid + b*1024, b=0..3
    float4 acc[4] = {};
    float4 xv[4];
    #pragma unroll
    for (int b = 0; b < 4; ++b) xv[b] = xs4[tid + b * 256];
    #pragma unroll
    for (int jg = 0; jg < 32; ++jg) {
        float4 wv = *(const float4*)&wsm[4 * jg];
        #pragma unroll
        for (int b = 0; b < 4; ++b) {
            float4 xn = xs4[tid + b * 256 + jg + 1];
            acc[b].x += wv.x * xv[b].x + wv.y * xv[b].y + wv.z * xv[b].z + wv.w * xv[b].w;
            acc[b].y += wv.x * xv[b].y + wv.y * xv[b].z + wv.z * xv[b].w + wv.w * xn.x;
            acc[b].z += wv.x * xv[b].z + wv.y * xv[b].w + wv.z * xn.x  + wv.w * xn.y;
            acc[b].w += wv.x * xv[b].w + wv.y * xn.x  + wv.z * xn.y  + wv.w * xn.z;
            xv[b] = xn;
        }
    }
    const float w128 = wsm[128];
    float4* Yr4 = (float4*)(Y + (size_t)j * 4096);
    #pragma unroll
    for (int b = 0; b < 4; ++b) {
        acc[b].x += w128 * xv[b].x; acc[b].y += w128 * xv[b].y;
        acc[b].z += w128 * xv[b].z; acc[b].w += w128 * xv[b].w;
        Yr4[tid + b * 256] = acc[b];
    }
}

// ---------- fp32 transpose: in [R][C] -> out [C][R] ----------
__global__ void transpose_kernel(const float* __restrict__ in, float* __restrict__ out,
                                 int R, int C) {
    __shared__ float t[32][33];
    int bx = blockIdx.x * 32;
    int by = blockIdx.y * 32;
    int tx = threadIdx.x & 31, ty = threadIdx.x >> 5;
    #pragma unroll
    for (int i = ty; i < 32; i += 8)
        t[i][tx] = in[(size_t)(by + i) * C + bx + tx];
    __syncthreads();
    #pragma unroll
    for (int i = ty; i < 32; i += 8)
        out[(size_t)(bx + i) * R + by + tx] = t[tx][i];
}

// ---------- split-K reduce: out = act(scale * sum_s P[s] + bias) ----------
// idx indexes float4s; row = idx/ncols4, col4 = idx%ncols4; out at row*outstride4+col4
template<int GELU>
__global__ void reduce_kernel(const float* __restrict__ P, size_t zstride, int S,
                              const float* __restrict__ bias, float scale,
                              float* __restrict__ out, int ncols4, int outstride4) {
    int idx = blockIdx.x * 256 + threadIdx.x;
    float4 a = ((const float4*)P)[idx];
    for (int s = 1; s < S; ++s) {
        float4 p = ((const float4*)(P + (size_t)s * zstride))[idx];
        a.x += p.x; a.y += p.y; a.z += p.z; a.w += p.w;
    }
    a.x *= scale; a.y *= scale; a.z *= scale; a.w *= scale;
    int row = idx / ncols4, col4 = idx - row * ncols4;
    if (bias) {
        float4 b = ((const float4*)bias)[col4];
        a.x += b.x; a.y += b.y; a.z += b.z; a.w += b.w;
    }
    if (GELU) {
        a.x = gelu_f(a.x); a.y = gelu_f(a.y);
        a.z = gelu_f(a.z); a.w = gelu_f(a.w);
    }
    ((float4*)out)[(size_t)row * outstride4 + col4] = a;
}

// ---------- MFMA GEMM:  P[z] = A[M,K] @ B[N,K]^T  (split-K partials, plain stores) ----------
// fp32 in, fp16 MFMA, fp32 accumulate. 128x128 tile, BK=64, 4 waves (2x2),
// wave tile 64x64 = 4x4 mfma_16x16x32 (x2 k-steps). Register-prefetch pipeline.
#define LDS_GRP 136
__global__ __launch_bounds__(256, 2)
void gemm_bt(const float* __restrict__ A, int lda,
             const float* __restrict__ B, int ldb,
             float* __restrict__ P, int ldc, size_t zstride,
             int K_chunk) {
    __shared__ _Float16 sA[64 * LDS_GRP];
    __shared__ _Float16 sB[64 * LDS_GRP];
    const int tid  = threadIdx.x;
    const int wv   = tid >> 6, lane = tid & 63;
    const int wm   = (wv >> 1) * 64, wn = (wv & 1) * 64;
    const int quad = lane >> 4, l16 = lane & 15;
    const int srow = tid >> 4;        // 0..15
    const int sk   = (tid & 15) * 4;  // 0..60

    const size_t k0 = (size_t)blockIdx.z * (size_t)K_chunk;
    const float* Ab = A + (size_t)blockIdx.x * 128 * (size_t)lda + k0;
    const float* Bb = B + (size_t)blockIdx.y * 128 * (size_t)ldb + k0;

    const int wroff = (sk >> 3) * LDS_GRP + srow * 8 + (sk & 4);

    f32x4 acc[4][4] = {};
    float4 av[8], bv[8];
    #pragma unroll
    for (int p = 0; p < 8; ++p) {
        av[p] = *(const float4*)(Ab + (size_t)(p * 16 + srow) * lda + sk);
        bv[p] = *(const float4*)(Bb + (size_t)(p * 16 + srow) * ldb + sk);
    }

    const int nk = K_chunk >> 6;
    for (int kt = 0; ; ++kt) {
        __syncthreads();
        #pragma unroll
        for (int p = 0; p < 8; ++p) {
            int off = p * 8 * LDS_GRP + wroff;
            *(f16x4*)&sA[off] = cvt4(av[p]);
            *(f16x4*)&sB[off] = cvt4(bv[p]);
        }
        __syncthreads();
        if (kt + 1 < nk) {
            const float* An = Ab + (size_t)(kt + 1) * 64;
            const float* Bn = Bb + (size_t)(kt + 1) * 64;
            #pragma unroll
            for (int p = 0; p < 8; ++p) {
                av[p] = *(const float4*)(An + (size_t)(p * 16 + srow) * lda + sk);
                bv[p] = *(const float4*)(Bn + (size_t)(p * 16 + srow) * ldb + sk);
            }
        }
        #pragma unroll
        for (int ks = 0; ks < 2; ++ks) {
            f16x8 af[4], bfr[4];
            #pragma unroll
            for (int i = 0; i < 4; ++i) {
                af[i]  = *(const f16x8*)&sA[(((wm >> 4) + i) * 8 + ks * 4 + quad) * LDS_GRP + l16 * 8];
                bfr[i] = *(const f16x8*)&sB[(((wn >> 4) + i) * 8 + ks * 4 + quad) * LDS_GRP + l16 * 8];
            }
            #pragma unroll
            for (int mi = 0; mi < 4; ++mi)
                #pragma unroll
                for (int ni = 0; ni < 4; ++ni)
                    acc[mi][ni] = __builtin_amdgcn_mfma_f32_16x16x32_f16(af[mi], bfr[ni], acc[mi][ni], 0, 0, 0);
        }
        if (kt + 1 >= nk) break;
    }

    // epilogue: plain stores to this chunk's partial buffer
    float* Cp = P + (size_t)blockIdx.z * zstride;
    #pragma unroll
    for (int mi = 0; mi < 4; ++mi)
        #pragma unroll
        for (int ni = 0; ni < 4; ++ni) {
            size_t colg = (size_t)blockIdx.y * 128 + wn + ni * 16 + l16;
            #pragma unroll
            for (int rr = 0; rr < 4; ++rr) {
                size_t rowg = (size_t)blockIdx.x * 128 + wm + mi * 16 + quad * 4 + rr;
                Cp[rowg * (size_t)ldc + colg] = acc[mi][ni][rr];
            }
        }
}

extern "C" void kernel_launch(void* const* d_in, const int* in_sizes, int n_in,
                              void* d_out, int out_size, void* d_ws, size_t ws_size,
                              hipStream_t stream) {
    const float* X    = (const float*)d_in[0];
    const float* wnw1 = (const float*)d_in[1];
    const float* wnb1 = (const float*)d_in[2];
    const float* wnw2 = (const float*)d_in[3];
    const float* wnb2 = (const float*)d_in[4];
    const float* fc1w = (const float*)d_in[5];
    const float* fc1b = (const float*)d_in[6];
    const float* fc2w = (const float*)d_in[7];
    const float* fc2b = (const float*)d_in[8];
    const float* fc3w = (const float*)d_in[9];
    const float* fc3b = (const float*)d_in[10];
    const float* proj = (const float*)d_in[11];
    float* out = (float*)d_out;

    // ---- workspace layout (floats), liveness-aliased, total 50.6 MB ----
    float* ws   = (float*)d_ws;
    float* z    = ws;                      // 2097152   [256,8192]
    float* h1   = z   + 2097152;           // 1048576   (also h3)
    float* h2   = h1  + 1048576;           // 1048576   (also h3T)
    float* cov  = h2  + 1048576;           // 65536
    float* wbuf = cov + 65536;             // 256
    float* P    = wbuf + 256;              // 8388608   split-K partials
    float* Xc   = P;                       // alias: live only until cov gemm done
    float* Yb   = P + 1048576;             // alias
    float* XT   = P + 2097152;             // alias: live until ci gemm done
    float* Pcov = P + 3145728;             // 32 x 65536 cov partials
    float* h3   = h1;                      // h1 dead after fc2 gemm
    float* h3T  = h2;                      // h2 dead after fc3 gemm

    weightnet_kernel<<<1, 192, 0, stream>>>(wnw1, wnb1, wnw2, wnb2, wbuf);
    center_conv_kernel<<<256, 256, 0, stream>>>(X, wbuf, Xc, Yb, z);
    transpose_kernel<<<dim3(128, 8), 256, 0, stream>>>(X, XT, 256, 4096);

    // cov = (1/4096) * Xc @ Yb^T   [256,256], K=4096, split-K 32
    gemm_bt<<<dim3(2, 2, 32), 256, 0, stream>>>(Xc, 4096, Yb, 4096, Pcov, 256, 65536, 128);
    reduce_kernel<0><<<64, 256, 0, stream>>>(Pcov, 65536, 32, nullptr, 1.0f / 4096.0f, cov, 64, 64);

    // cov_inter = cov @ X -> z[:, 4096:]   [256,4096], K=256, split-K 2
    gemm_bt<<<dim3(2, 32, 2), 256, 0, stream>>>(cov, 256, XT, 256, P, 4096, 1048576, 128);
    reduce_kernel<0><<<1024, 256, 0, stream>>>(P, 1048576, 2, nullptr, 1.0f, z + 4096, 1024, 2048);

    // fc1: h1 = gelu(z @ fc1_w^T + b1)   [256,4096], K=8192, split-K 8
    gemm_bt<<<dim3(2, 32, 8), 256, 0, stream>>>(z, 8192, fc1w, 8192, P, 4096, 1048576, 1024);
    reduce_kernel<1><<<1024, 256, 0, stream>>>(P, 1048576, 8, fc1b, 1.0f, h1, 1024, 1024);

    // fc2: h2 = gelu(h1 @ fc2_w^T + b2)   K=4096, split-K 8
    gemm_bt<<<dim3(2, 32, 8), 256, 0, stream>>>(h1, 4096, fc2w, 4096, P, 4096, 1048576, 512);
    reduce_kernel<1><<<1024, 256, 0, stream>>>(P, 1048576, 8, fc2b, 1.0f, h2, 1024, 1024);

    // fc3: h3 = h2 @ fc3_w^T + b3   K=4096, split-K 8  (no gelu)
    gemm_bt<<<dim3(2, 32, 8), 256, 0, stream>>>(h2, 4096, fc3w, 4096, P, 4096, 1048576, 512);
    reduce_kernel<0><<<1024, 256, 0, stream>>>(P, 1048576, 8, fc3b, 1.0f, h3, 1024, 1024);

    // h3T = h3^T  [4096,256]
    transpose_kernel<<<dim3(128, 8), 256, 0, stream>>>(h3, h3T, 256, 4096);

    // out = proj @ h3   [512,4096], K=256, split-K 2
    gemm_bt<<<dim3(4, 32, 2), 256, 0, stream>>>(proj, 256, h3T, 256, P, 4096, 2097152, 128);
    reduce_kernel<0><<<2048, 256, 0, stream>>>(P, 2097152, 2, nullptr, 1.0f, out, 1024, 1024);
}

// Round 3
// 454.542 us; speedup vs baseline: 1.2135x; 1.0241x over previous
//
#include <hip/hip_runtime.h>
#include <math.h>

// ---------- types ----------
typedef float  f32x4 __attribute__((ext_vector_type(4)));
typedef _Float16 f16x8 __attribute__((ext_vector_type(8)));
typedef _Float16 f16x4 __attribute__((ext_vector_type(4)));

__device__ __forceinline__ float gelu_f(float x) {
    return 0.5f * x * (1.0f + erff(x * 0.70710678118654752440f));
}

__device__ __forceinline__ f16x4 cvt4(float4 v) {
    f16x4 h;
    h.x = (_Float16)v.x; h.y = (_Float16)v.y;
    h.z = (_Float16)v.z; h.w = (_Float16)v.w;
    return h;
}

// ---------- weight_net: w[l] for lags -64..64 ----------
__global__ void weightnet_kernel(const float* __restrict__ w1, const float* __restrict__ b1,
                                 const float* __restrict__ w2, const float* __restrict__ b2,
                                 float* __restrict__ wout) {
    int l = threadIdx.x;
    if (l < 129) {
        float lag = (float)(l - 64);
        float acc = b2[0];
        for (int k = 0; k < 64; ++k) {
            float h = lag * w1[k] + b1[k];
            acc += gelu_f(h) * w2[k];
        }
        wout[l] = acc;
    }
}

// ---------- fused: row mean + center + 129-tap conv (register FIR) ----------
// __launch_bounds__(256): without it hipcc assumes 1024-thread blocks and caps
// VGPRs at 64 -> vbuf/xv/acc spill to scratch -> 254 MB of HBM traffic, 111 us.
__global__ __launch_bounds__(256)
void center_conv_kernel(const float* __restrict__ X,
                        const float* __restrict__ w, float* __restrict__ Xc,
                        float* __restrict__ Y, float* __restrict__ z) {
    __shared__ float xs[4224];            // 64 pad + 4096 + 64 pad
    __shared__ float wsm[132];
    __shared__ float ps[4];
    const int j = blockIdx.x, tid = threadIdx.x;
    float4* xs4 = (float4*)xs;

    if (tid < 64) { xs[tid] = 0.f; xs[4160 + tid] = 0.f; }
    if (tid < 132) wsm[tid] = (tid < 129) ? w[tid] : 0.f;

    const float4* Xr4 = (const float4*)(X + (size_t)j * 4096);
    float4* zr4 = (float4*)(z + (size_t)j * 8192);
    float s = 0.f;
    float4 vbuf[4];
    #pragma unroll
    for (int k = 0; k < 4; ++k) {
        int c4 = tid + k * 256;
        float4 v = Xr4[c4];
        vbuf[k] = v;
        xs4[16 + c4] = v;
        zr4[c4] = v;
        s += v.x + v.y + v.z + v.w;
    }
    #pragma unroll
    for (int o = 32; o > 0; o >>= 1) s += __shfl_down(s, o, 64);
    if ((tid & 63) == 0) ps[tid >> 6] = s;
    __syncthreads();
    const float m = (ps[0] + ps[1] + ps[2] + ps[3]) * (1.0f / 4096.0f);

    float4* Xc4 = (float4*)(Xc + (size_t)j * 4096);
    #pragma unroll
    for (int k = 0; k < 4; ++k) {
        int c4 = tid + k * 256;
        float4 v = vbuf[k];
        v.x -= m; v.y -= m; v.z -= m; v.w -= m;
        xs4[16 + c4] = v;
        Xc4[c4] = v;
    }
    __syncthreads();

    // conv: thread handles outputs t0 = 4*tid + b*1024, b=0..3
    float4 acc[4] = {};
    float4 xv[4];
    #pragma unroll
    for (int b = 0; b < 4; ++b) xv[b] = xs4[tid + b * 256];
    #pragma unroll
    for (int jg = 0; jg < 32; ++jg) {
        float4 wv = *(const float4*)&wsm[4 * jg];
        #pragma unroll
        for (int b = 0; b < 4; ++b) {
            float4 xn = xs4[tid + b * 256 + jg + 1];
            acc[b].x += wv.x * xv[b].x + wv.y * xv[b].y + wv.z * xv[b].z + wv.w * xv[b].w;
            acc[b].y += wv.x * xv[b].y + wv.y * xv[b].z + wv.z * xv[b].w + wv.w * xn.x;
            acc[b].z += wv.x * xv[b].z + wv.y * xv[b].w + wv.z * xn.x  + wv.w * xn.y;
            acc[b].w += wv.x * xv[b].w + wv.y * xn.x  + wv.z * xn.y  + wv.w * xn.z;
            xv[b] = xn;
        }
    }
    const float w128 = wsm[128];
    float4* Yr4 = (float4*)(Y + (size_t)j * 4096);
    #pragma unroll
    for (int b = 0; b < 4; ++b) {
        acc[b].x += w128 * xv[b].x; acc[b].y += w128 * xv[b].y;
        acc[b].z += w128 * xv[b].z; acc[b].w += w128 * xv[b].w;
        Yr4[tid + b * 256] = acc[b];
    }
}

// ---------- fp32 transpose: in [R][C] -> out [C][R] ----------
__global__ void transpose_kernel(const float* __restrict__ in, float* __restrict__ out,
                                 int R, int C) {
    __shared__ float t[32][33];
    int bx = blockIdx.x * 32;
    int by = blockIdx.y * 32;
    int tx = threadIdx.x & 31, ty = threadIdx.x >> 5;
    #pragma unroll
    for (int i = ty; i < 32; i += 8)
        t[i][tx] = in[(size_t)(by + i) * C + bx + tx];
    __syncthreads();
    #pragma unroll
    for (int i = ty; i < 32; i += 8)
        out[(size_t)(bx + i) * R + by + tx] = t[tx][i];
}

// ---------- split-K reduce: out = act(scale * sum_s P[s] + bias) ----------
template<int GELU>
__global__ void reduce_kernel(const float* __restrict__ P, size_t zstride, int S,
                              const float* __restrict__ bias, float scale,
                              float* __restrict__ out, int ncols4, int outstride4) {
    int idx = blockIdx.x * 256 + threadIdx.x;
    float4 a = ((const float4*)P)[idx];
    for (int s = 1; s < S; ++s) {
        float4 p = ((const float4*)(P + (size_t)s * zstride))[idx];
        a.x += p.x; a.y += p.y; a.z += p.z; a.w += p.w;
    }
    a.x *= scale; a.y *= scale; a.z *= scale; a.w *= scale;
    int row = idx / ncols4, col4 = idx - row * ncols4;
    if (bias) {
        float4 b = ((const float4*)bias)[col4];
        a.x += b.x; a.y += b.y; a.z += b.z; a.w += b.w;
    }
    if (GELU) {
        a.x = gelu_f(a.x); a.y = gelu_f(a.y);
        a.z = gelu_f(a.z); a.w = gelu_f(a.w);
    }
    ((float4*)out)[(size_t)row * outstride4 + col4] = a;
}

// ---------- MFMA GEMM:  P[z] = A[M,K] @ B[N,K]^T  (split-K partials) ----------
// fp32 in, fp16 MFMA, fp32 accumulate. 128x128 tile, BK=32, 4 waves (2x2),
// wave tile 64x64 = 4x4 mfma_16x16x32. Double-buffered LDS (1 barrier/iter)
// + depth-2 register prefetch: loads for tile kt+3 issued at iter kt,
// ds-written at iter kt+2 -> ~2-iteration in-flight window covers HBM latency.
// Reg sets a0/b0, a1/b1 are statically named (tile t lives in set t&1).
#define LDS_GRP 136
__global__ __launch_bounds__(256, 2)
void gemm_bt(const float* __restrict__ A, int lda,
             const float* __restrict__ B, int ldb,
             float* __restrict__ P, int ldc, size_t zstride,
             int K_chunk) {
    __shared__ _Float16 sA[2][32 * LDS_GRP];
    __shared__ _Float16 sB[2][32 * LDS_GRP];
    const int tid  = threadIdx.x;
    const int wv   = tid >> 6, lane = tid & 63;
    const int wm   = (wv >> 1) * 64, wn = (wv & 1) * 64;
    const int quad = lane >> 4, l16 = lane & 15;
    const int srow = tid >> 3;        // 0..31
    const int sk   = (tid & 7) * 4;   // 0..28
    const int koct = sk >> 3;         // 0..3
    const int k4   = sk & 4;

    const size_t k0 = (size_t)blockIdx.z * (size_t)K_chunk;
    const float* Ab = A + (size_t)blockIdx.x * 128 * (size_t)lda + k0;
    const float* Bb = B + (size_t)blockIdx.y * 128 * (size_t)ldb + k0;

    f32x4 acc[4][4] = {};
    float4 a0[4], b0[4], a1[4], b1[4];

#define LOADT(aset, bset, kt_) do {                                          \
    const float* An_ = Ab + (size_t)(kt_) * 32;                              \
    const float* Bn_ = Bb + (size_t)(kt_) * 32;                              \
    _Pragma("unroll")                                                        \
    for (int p = 0; p < 4; ++p) {                                            \
        aset[p] = *(const float4*)(An_ + (size_t)(p * 32 + srow) * lda + sk);\
        bset[p] = *(const float4*)(Bn_ + (size_t)(p * 32 + srow) * ldb + sk);\
    } } while (0)

#define STORET(buf_, aset, bset) do {                                        \
    _Pragma("unroll")                                                        \
    for (int p = 0; p < 4; ++p) {                                            \
        int off = ((p * 2 + (srow >> 4)) * 4 + koct) * LDS_GRP               \
                  + (srow & 15) * 8 + k4;                                    \
        *(f16x4*)&sA[buf_][off] = cvt4(aset[p]);                             \
        *(f16x4*)&sB[buf_][off] = cvt4(bset[p]);                             \
    } } while (0)

#define MFMAT(buf_) do {                                                     \
    f16x8 af[4], bfr[4];                                                     \
    _Pragma("unroll")                                                        \
    for (int i = 0; i < 4; ++i) {                                            \
        af[i]  = *(const f16x8*)&sA[buf_][(((wm >> 4) + i) * 4 + quad) * LDS_GRP + l16 * 8]; \
        bfr[i] = *(const f16x8*)&sB[buf_][(((wn >> 4) + i) * 4 + quad) * LDS_GRP + l16 * 8]; \
    }                                                                        \
    _Pragma("unroll")                                                        \
    for (int mi = 0; mi < 4; ++mi)                                           \
        _Pragma("unroll")                                                    \
        for (int ni = 0; ni < 4; ++ni)                                       \
            acc[mi][ni] = __builtin_amdgcn_mfma_f32_16x16x32_f16(af[mi], bfr[ni], acc[mi][ni], 0, 0, 0); \
    } while (0)

    const int nk = K_chunk >> 5;
    // prologue: tiles 0,1,2 issued; tile0 staged into buf0
    LOADT(a0, b0, 0);
    if (nk > 1) LOADT(a1, b1, 1);
    STORET(0, a0, b0);
    if (nk > 2) LOADT(a0, b0, 2);
    __syncthreads();

    for (int kt = 0; kt < nk; ++kt) {
        const int cur = kt & 1;
        if (kt + 1 < nk) {
            if ((kt + 1) & 1) {
                STORET(cur ^ 1, a1, b1);
                if (kt + 3 < nk) LOADT(a1, b1, kt + 3);
            } else {
                STORET(cur ^ 1, a0, b0);
                if (kt + 3 < nk) LOADT(a0, b0, kt + 3);
            }
        }
        MFMAT(cur);
        __syncthreads();
    }
#undef LOADT
#undef STORET
#undef MFMAT

    // epilogue: plain stores to this chunk's partial buffer
    float* Cp = P + (size_t)blockIdx.z * zstride;
    #pragma unroll
    for (int mi = 0; mi < 4; ++mi)
        #pragma unroll
        for (int ni = 0; ni < 4; ++ni) {
            size_t colg = (size_t)blockIdx.y * 128 + wn + ni * 16 + l16;
            #pragma unroll
            for (int rr = 0; rr < 4; ++rr) {
                size_t rowg = (size_t)blockIdx.x * 128 + wm + mi * 16 + quad * 4 + rr;
                Cp[rowg * (size_t)ldc + colg] = acc[mi][ni][rr];
            }
        }
}

extern "C" void kernel_launch(void* const* d_in, const int* in_sizes, int n_in,
                              void* d_out, int out_size, void* d_ws, size_t ws_size,
                              hipStream_t stream) {
    const float* X    = (const float*)d_in[0];
    const float* wnw1 = (const float*)d_in[1];
    const float* wnb1 = (const float*)d_in[2];
    const float* wnw2 = (const float*)d_in[3];
    const float* wnb2 = (const float*)d_in[4];
    const float* fc1w = (const float*)d_in[5];
    const float* fc1b = (const float*)d_in[6];
    const float* fc2w = (const float*)d_in[7];
    const float* fc2b = (const float*)d_in[8];
    const float* fc3w = (const float*)d_in[9];
    const float* fc3b = (const float*)d_in[10];
    const float* proj = (const float*)d_in[11];
    float* out = (float*)d_out;

    // ---- workspace layout (floats), liveness-aliased, total 50.6 MB ----
    float* ws   = (float*)d_ws;
    float* z    = ws;                      // 2097152   [256,8192]
    float* h1   = z   + 2097152;           // 1048576   (also h3)
    float* h2   = h1  + 1048576;           // 1048576   (also h3T)
    float* cov  = h2  + 1048576;           // 65536
    float* wbuf = cov + 65536;             // 256
    float* P    = wbuf + 256;              // 8388608   split-K partials
    float* Xc   = P;                       // alias: live only until cov gemm done
    float* Yb   = P + 1048576;             // alias
    float* XT   = P + 2097152;             // alias: live until ci gemm done
    float* Pcov = P + 3145728;             // 32 x 65536 cov partials
    float* h3   = h1;                      // h1 dead after fc2 gemm
    float* h3T  = h2;                      // h2 dead after fc3 gemm

    weightnet_kernel<<<1, 192, 0, stream>>>(wnw1, wnb1, wnw2, wnb2, wbuf);
    center_conv_kernel<<<256, 256, 0, stream>>>(X, wbuf, Xc, Yb, z);
    transpose_kernel<<<dim3(128, 8), 256, 0, stream>>>(X, XT, 256, 4096);

    // cov = (1/4096) * Xc @ Yb^T   [256,256], K=4096, split-K 32
    gemm_bt<<<dim3(2, 2, 32), 256, 0, stream>>>(Xc, 4096, Yb, 4096, Pcov, 256, 65536, 128);
    reduce_kernel<0><<<64, 256, 0, stream>>>(Pcov, 65536, 32, nullptr, 1.0f / 4096.0f, cov, 64, 64);

    // cov_inter = cov @ X -> z[:, 4096:]   [256,4096], K=256, split-K 2
    gemm_bt<<<dim3(2, 32, 2), 256, 0, stream>>>(cov, 256, XT, 256, P, 4096, 1048576, 128);
    reduce_kernel<0><<<1024, 256, 0, stream>>>(P, 1048576, 2, nullptr, 1.0f, z + 4096, 1024, 2048);

    // fc1: h1 = gelu(z @ fc1_w^T + b1)   [256,4096], K=8192, split-K 8
    gemm_bt<<<dim3(2, 32, 8), 256, 0, stream>>>(z, 8192, fc1w, 8192, P, 4096, 1048576, 1024);
    reduce_kernel<1><<<1024, 256, 0, stream>>>(P, 1048576, 8, fc1b, 1.0f, h1, 1024, 1024);

    // fc2: h2 = gelu(h1 @ fc2_w^T + b2)   K=4096, split-K 8
    gemm_bt<<<dim3(2, 32, 8), 256, 0, stream>>>(h1, 4096, fc2w, 4096, P, 4096, 1048576, 512);
    reduce_kernel<1><<<1024, 256, 0, stream>>>(P, 1048576, 8, fc2b, 1.0f, h2, 1024, 1024);

    // fc3: h3 = h2 @ fc3_w^T + b3   K=4096, split-K 8  (no gelu)
    gemm_bt<<<dim3(2, 32, 8), 256, 0, stream>>>(h2, 4096, fc3w, 4096, P, 4096, 1048576, 512);
    reduce_kernel<0><<<1024, 256, 0, stream>>>(P, 1048576, 8, fc3b, 1.0f, h3, 1024, 1024);

    // h3T = h3^T  [4096,256]
    transpose_kernel<<<dim3(128, 8), 256, 0, stream>>>(h3, h3T, 256, 4096);

    // out = proj @ h3   [512,4096], K=256, split-K 2
    gemm_bt<<<dim3(4, 32, 2), 256, 0, stream>>>(proj, 256, h3T, 256, P, 4096, 2097152, 128);
    reduce_kernel<0><<<2048, 256, 0, stream>>>(P, 2097152, 2, nullptr, 1.0f, out, 1024, 1024);
}

// Round 4
// 454.081 us; speedup vs baseline: 1.2147x; 1.0010x over previous
//
#include <hip/hip_runtime.h>
#include <math.h>

// ---------- types ----------
typedef float  f32x4 __attribute__((ext_vector_type(4)));
typedef _Float16 f16x8 __attribute__((ext_vector_type(8)));
typedef _Float16 f16x4 __attribute__((ext_vector_type(4)));

__device__ __forceinline__ float gelu_f(float x) {
    return 0.5f * x * (1.0f + erff(x * 0.70710678118654752440f));
}

__device__ __forceinline__ f16x4 cvt4(float4 v) {
    f16x4 h;
    h.x = (_Float16)v.x; h.y = (_Float16)v.y;
    h.z = (_Float16)v.z; h.w = (_Float16)v.w;
    return h;
}

// ---------- weight_net: w[l] for lags -64..64 ----------
__global__ void weightnet_kernel(const float* __restrict__ w1, const float* __restrict__ b1,
                                 const float* __restrict__ w2, const float* __restrict__ b2,
                                 float* __restrict__ wout) {
    int l = threadIdx.x;
    if (l < 129) {
        float lag = (float)(l - 64);
        float acc = b2[0];
        for (int k = 0; k < 64; ++k) {
            float h = lag * w1[k] + b1[k];
            acc += gelu_f(h) * w2[k];
        }
        wout[l] = acc;
    }
}

// ---------- fused: row mean + center + 129-tap conv (register FIR) ----------
// __launch_bounds__(256): without it hipcc assumes 1024-thread blocks and caps
// VGPRs at 64 -> vbuf/xv/acc spill to scratch -> 254 MB of HBM traffic, 111 us.
__global__ __launch_bounds__(256)
void center_conv_kernel(const float* __restrict__ X,
                        const float* __restrict__ w, float* __restrict__ Xc,
                        float* __restrict__ Y, float* __restrict__ z) {
    __shared__ float xs[4224];            // 64 pad + 4096 + 64 pad
    __shared__ float wsm[132];
    __shared__ float ps[4];
    const int j = blockIdx.x, tid = threadIdx.x;
    float4* xs4 = (float4*)xs;

    if (tid < 64) { xs[tid] = 0.f; xs[4160 + tid] = 0.f; }
    if (tid < 132) wsm[tid] = (tid < 129) ? w[tid] : 0.f;

    const float4* Xr4 = (const float4*)(X + (size_t)j * 4096);
    float4* zr4 = (float4*)(z + (size_t)j * 8192);
    float s = 0.f;
    float4 vbuf[4];
    #pragma unroll
    for (int k = 0; k < 4; ++k) {
        int c4 = tid + k * 256;
        float4 v = Xr4[c4];
        vbuf[k] = v;
        xs4[16 + c4] = v;
        zr4[c4] = v;
        s += v.x + v.y + v.z + v.w;
    }
    #pragma unroll
    for (int o = 32; o > 0; o >>= 1) s += __shfl_down(s, o, 64);
    if ((tid & 63) == 0) ps[tid >> 6] = s;
    __syncthreads();
    const float m = (ps[0] + ps[1] + ps[2] + ps[3]) * (1.0f / 4096.0f);

    float4* Xc4 = (float4*)(Xc + (size_t)j * 4096);
    #pragma unroll
    for (int k = 0; k < 4; ++k) {
        int c4 = tid + k * 256;
        float4 v = vbuf[k];
        v.x -= m; v.y -= m; v.z -= m; v.w -= m;
        xs4[16 + c4] = v;
        Xc4[c4] = v;
    }
    __syncthreads();

    // conv: thread handles outputs t0 = 4*tid + b*1024, b=0..3
    float4 acc[4] = {};
    float4 xv[4];
    #pragma unroll
    for (int b = 0; b < 4; ++b) xv[b] = xs4[tid + b * 256];
    #pragma unroll
    for (int jg = 0; jg < 32; ++jg) {
        float4 wv = *(const float4*)&wsm[4 * jg];
        #pragma unroll
        for (int b = 0; b < 4; ++b) {
            float4 xn = xs4[tid + b * 256 + jg + 1];
            acc[b].x += wv.x * xv[b].x + wv.y * xv[b].y + wv.z * xv[b].z + wv.w * xv[b].w;
            acc[b].y += wv.x * xv[b].y + wv.y * xv[b].z + wv.z * xv[b].w + wv.w * xn.x;
            acc[b].z += wv.x * xv[b].z + wv.y * xv[b].w + wv.z * xn.x  + wv.w * xn.y;
            acc[b].w += wv.x * xv[b].w + wv.y * xn.x  + wv.z * xn.y  + wv.w * xn.z;
            xv[b] = xn;
        }
    }
    const float w128 = wsm[128];
    float4* Yr4 = (float4*)(Y + (size_t)j * 4096);
    #pragma unroll
    for (int b = 0; b < 4; ++b) {
        acc[b].x += w128 * xv[b].x; acc[b].y += w128 * xv[b].y;
        acc[b].z += w128 * xv[b].z; acc[b].w += w128 * xv[b].w;
        Yr4[tid + b * 256] = acc[b];
    }
}

// ---------- fp32 transpose: in [R][C] -> out [C][R] ----------
__global__ void transpose_kernel(const float* __restrict__ in, float* __restrict__ out,
                                 int R, int C) {
    __shared__ float t[32][33];
    int bx = blockIdx.x * 32;
    int by = blockIdx.y * 32;
    int tx = threadIdx.x & 31, ty = threadIdx.x >> 5;
    #pragma unroll
    for (int i = ty; i < 32; i += 8)
        t[i][tx] = in[(size_t)(by + i) * C + bx + tx];
    __syncthreads();
    #pragma unroll
    for (int i = ty; i < 32; i += 8)
        out[(size_t)(bx + i) * R + by + tx] = t[tx][i];
}

// ---------- split-K reduce: out = act(scale * sum_s P[s] + bias) ----------
template<int GELU>
__global__ void reduce_kernel(const float* __restrict__ P, size_t zstride, int S,
                              const float* __restrict__ bias, float scale,
                              float* __restrict__ out, int ncols4, int outstride4) {
    int idx = blockIdx.x * 256 + threadIdx.x;
    float4 a = ((const float4*)P)[idx];
    for (int s = 1; s < S; ++s) {
        float4 p = ((const float4*)(P + (size_t)s * zstride))[idx];
        a.x += p.x; a.y += p.y; a.z += p.z; a.w += p.w;
    }
    a.x *= scale; a.y *= scale; a.z *= scale; a.w *= scale;
    int row = idx / ncols4, col4 = idx - row * ncols4;
    if (bias) {
        float4 b = ((const float4*)bias)[col4];
        a.x += b.x; a.y += b.y; a.z += b.z; a.w += b.w;
    }
    if (GELU) {
        a.x = gelu_f(a.x); a.y = gelu_f(a.y);
        a.z = gelu_f(a.z); a.w = gelu_f(a.w);
    }
    ((float4*)out)[(size_t)row * outstride4 + col4] = a;
}

// ---------- MFMA GEMM:  P[z] = A[M,K] @ B[N,K]^T  (split-K partials) ----------
// fp32 in, fp16 MFMA, fp32 accumulate. 128x128 tile, BK=32, 4 waves (2x2),
// wave tile 64x64 = 4x4 mfma_16x16x32. Double-buffered LDS, depth-2 register
// prefetch. KEY (T4): raw s_barrier + lgkmcnt(0)-only drain. __syncthreads()
// would emit s_waitcnt vmcnt(0) before every barrier, draining the global-load
// pipeline each iteration (measured: 6000 cyc/iter vs ~500 critical path).
// With lgkmcnt-only drain, loads for tiles kt+1..kt+3 stay in flight across
// barriers; STORET's consumers get compiler-counted vmcnt(N>0) waits.
#define LDS_GRP 136
#define BARRIER_LDS() do {                                   \
    asm volatile("s_waitcnt lgkmcnt(0)" ::: "memory");       \
    __builtin_amdgcn_s_barrier();                            \
    asm volatile("" ::: "memory");                           \
} while (0)

__global__ __launch_bounds__(256, 2)
void gemm_bt(const float* __restrict__ A, int lda,
             const float* __restrict__ B, int ldb,
             float* __restrict__ P, int ldc, size_t zstride,
             int K_chunk) {
    __shared__ _Float16 sA[2][32 * LDS_GRP];
    __shared__ _Float16 sB[2][32 * LDS_GRP];
    const int tid  = threadIdx.x;
    const int wv   = tid >> 6, lane = tid & 63;
    const int wm   = (wv >> 1) * 64, wn = (wv & 1) * 64;
    const int quad = lane >> 4, l16 = lane & 15;
    const int srow = tid >> 3;        // 0..31
    const int sk   = (tid & 7) * 4;   // 0..28
    const int koct = sk >> 3;         // 0..3
    const int k4   = sk & 4;

    const size_t k0 = (size_t)blockIdx.z * (size_t)K_chunk;
    const float* Ab = A + (size_t)blockIdx.x * 128 * (size_t)lda + k0;
    const float* Bb = B + (size_t)blockIdx.y * 128 * (size_t)ldb + k0;

    f32x4 acc[4][4] = {};
    float4 a0[4], b0[4], a1[4], b1[4];

#define LOADT(aset, bset, kt_) do {                                          \
    const float* An_ = Ab + (size_t)(kt_) * 32;                              \
    const float* Bn_ = Bb + (size_t)(kt_) * 32;                              \
    _Pragma("unroll")                                                        \
    for (int p = 0; p < 4; ++p) {                                            \
        aset[p] = *(const float4*)(An_ + (size_t)(p * 32 + srow) * lda + sk);\
        bset[p] = *(const float4*)(Bn_ + (size_t)(p * 32 + srow) * ldb + sk);\
    } } while (0)

#define STORET(buf_, aset, bset) do {                                        \
    _Pragma("unroll")                                                        \
    for (int p = 0; p < 4; ++p) {                                            \
        int off = ((p * 2 + (srow >> 4)) * 4 + koct) * LDS_GRP               \
                  + (srow & 15) * 8 + k4;                                    \
        *(f16x4*)&sA[buf_][off] = cvt4(aset[p]);                             \
        *(f16x4*)&sB[buf_][off] = cvt4(bset[p]);                             \
    } } while (0)

#define MFMAT(buf_) do {                                                     \
    f16x8 af[4], bfr[4];                                                     \
    _Pragma("unroll")                                                        \
    for (int i = 0; i < 4; ++i) {                                            \
        af[i]  = *(const f16x8*)&sA[buf_][(((wm >> 4) + i) * 4 + quad) * LDS_GRP + l16 * 8]; \
        bfr[i] = *(const f16x8*)&sB[buf_][(((wn >> 4) + i) * 4 + quad) * LDS_GRP + l16 * 8]; \
    }                                                                        \
    _Pragma("unroll")                                                        \
    for (int mi = 0; mi < 4; ++mi)                                           \
        _Pragma("unroll")                                                    \
        for (int ni = 0; ni < 4; ++ni)                                       \
            acc[mi][ni] = __builtin_amdgcn_mfma_f32_16x16x32_f16(af[mi], bfr[ni], acc[mi][ni], 0, 0, 0); \
    } while (0)

    const int nk = K_chunk >> 5;
    // prologue: tiles 0,1,2 issued; tile0 staged into buf0
    LOADT(a0, b0, 0);
    if (nk > 1) LOADT(a1, b1, 1);
    STORET(0, a0, b0);
    if (nk > 2) LOADT(a0, b0, 2);
    BARRIER_LDS();

    for (int kt = 0; kt < nk; ++kt) {
        const int cur = kt & 1;
        if (kt + 1 < nk) {
            if ((kt + 1) & 1) {
                STORET(cur ^ 1, a1, b1);
                if (kt + 3 < nk) LOADT(a1, b1, kt + 3);
            } else {
                STORET(cur ^ 1, a0, b0);
                if (kt + 3 < nk) LOADT(a0, b0, kt + 3);
            }
        }
        MFMAT(cur);
        BARRIER_LDS();
    }
#undef LOADT
#undef STORET
#undef MFMAT

    // epilogue: plain stores to this chunk's partial buffer
    float* Cp = P + (size_t)blockIdx.z * zstride;
    #pragma unroll
    for (int mi = 0; mi < 4; ++mi)
        #pragma unroll
        for (int ni = 0; ni < 4; ++ni) {
            size_t colg = (size_t)blockIdx.y * 128 + wn + ni * 16 + l16;
            #pragma unroll
            for (int rr = 0; rr < 4; ++rr) {
                size_t rowg = (size_t)blockIdx.x * 128 + wm + mi * 16 + quad * 4 + rr;
                Cp[rowg * (size_t)ldc + colg] = acc[mi][ni][rr];
            }
        }
}

extern "C" void kernel_launch(void* const* d_in, const int* in_sizes, int n_in,
                              void* d_out, int out_size, void* d_ws, size_t ws_size,
                              hipStream_t stream) {
    const float* X    = (const float*)d_in[0];
    const float* wnw1 = (const float*)d_in[1];
    const float* wnb1 = (const float*)d_in[2];
    const float* wnw2 = (const float*)d_in[3];
    const float* wnb2 = (const float*)d_in[4];
    const float* fc1w = (const float*)d_in[5];
    const float* fc1b = (const float*)d_in[6];
    const float* fc2w = (const float*)d_in[7];
    const float* fc2b = (const float*)d_in[8];
    const float* fc3w = (const float*)d_in[9];
    const float* fc3b = (const float*)d_in[10];
    const float* proj = (const float*)d_in[11];
    float* out = (float*)d_out;

    // ---- workspace layout (floats), liveness-aliased, total 50.6 MB ----
    float* ws   = (float*)d_ws;
    float* z    = ws;                      // 2097152   [256,8192]
    float* h1   = z   + 2097152;           // 1048576   (also h3)
    float* h2   = h1  + 1048576;           // 1048576   (also h3T)
    float* cov  = h2  + 1048576;           // 65536
    float* wbuf = cov + 65536;             // 256
    float* P    = wbuf + 256;              // 8388608   split-K partials
    float* Xc   = P;                       // alias: live only until cov gemm done
    float* Yb   = P + 1048576;             // alias
    float* XT   = P + 2097152;             // alias: live until ci gemm done
    float* Pcov = P + 3145728;             // 32 x 65536 cov partials
    float* h3   = h1;                      // h1 dead after fc2 gemm
    float* h3T  = h2;                      // h2 dead after fc3 gemm

    weightnet_kernel<<<1, 192, 0, stream>>>(wnw1, wnb1, wnw2, wnb2, wbuf);
    center_conv_kernel<<<256, 256, 0, stream>>>(X, wbuf, Xc, Yb, z);
    transpose_kernel<<<dim3(128, 8), 256, 0, stream>>>(X, XT, 256, 4096);

    // cov = (1/4096) * Xc @ Yb^T   [256,256], K=4096, split-K 32
    gemm_bt<<<dim3(2, 2, 32), 256, 0, stream>>>(Xc, 4096, Yb, 4096, Pcov, 256, 65536, 128);
    reduce_kernel<0><<<64, 256, 0, stream>>>(Pcov, 65536, 32, nullptr, 1.0f / 4096.0f, cov, 64, 64);

    // cov_inter = cov @ X -> z[:, 4096:]   [256,4096], K=256, split-K 2
    gemm_bt<<<dim3(2, 32, 2), 256, 0, stream>>>(cov, 256, XT, 256, P, 4096, 1048576, 128);
    reduce_kernel<0><<<1024, 256, 0, stream>>>(P, 1048576, 2, nullptr, 1.0f, z + 4096, 1024, 2048);

    // fc1: h1 = gelu(z @ fc1_w^T + b1)   [256,4096], K=8192, split-K 8
    gemm_bt<<<dim3(2, 32, 8), 256, 0, stream>>>(z, 8192, fc1w, 8192, P, 4096, 1048576, 1024);
    reduce_kernel<1><<<1024, 256, 0, stream>>>(P, 1048576, 8, fc1b, 1.0f, h1, 1024, 1024);

    // fc2: h2 = gelu(h1 @ fc2_w^T + b2)   K=4096, split-K 8
    gemm_bt<<<dim3(2, 32, 8), 256, 0, stream>>>(h1, 4096, fc2w, 4096, P, 4096, 1048576, 512);
    reduce_kernel<1><<<1024, 256, 0, stream>>>(P, 1048576, 8, fc2b, 1.0f, h2, 1024, 1024);

    // fc3: h3 = h2 @ fc3_w^T + b3   K=4096, split-K 8  (no gelu)
    gemm_bt<<<dim3(2, 32, 8), 256, 0, stream>>>(h2, 4096, fc3w, 4096, P, 4096, 1048576, 512);
    reduce_kernel<0><<<1024, 256, 0, stream>>>(P, 1048576, 8, fc3b, 1.0f, h3, 1024, 1024);

    // h3T = h3^T  [4096,256]
    transpose_kernel<<<dim3(128, 8), 256, 0, stream>>>(h3, h3T, 256, 4096);

    // out = proj @ h3   [512,4096], K=256, split-K 2
    gemm_bt<<<dim3(4, 32, 2), 256, 0, stream>>>(proj, 256, h3T, 256, P, 4096, 2097152, 128);
    reduce_kernel<0><<<2048, 256, 0, stream>>>(P, 2097152, 2, nullptr, 1.0f, out, 1024, 1024);
}